// Round 1
// baseline (435.968 us; speedup 1.0000x reference)
//
#include <hip/hip_runtime.h>
#include <hip/hip_bf16.h>
#include <stdint.h>

#define H2    512
#define BATCH 32
#define SEQ   4096
#define BM    128
#define BK    64
#define NKT   16          // K-tiles: 1024 / 64

typedef __attribute__((ext_vector_type(4))) float f32x4;
typedef __attribute__((ext_vector_type(8))) short bf16x8;

typedef __attribute__((address_space(3))) unsigned int       as3_uint;
typedef const __attribute__((address_space(1))) unsigned int as1_uint;

// RNE fp32 -> bf16
__device__ __forceinline__ unsigned short f2bf(float f) {
    union { float f; unsigned u; } v; v.f = f;
    unsigned r = v.u + 0x7FFF + ((v.u >> 16) & 1);
    return (unsigned short)(r >> 16);
}

__device__ __forceinline__ float fast_tanh(float x) {
    // tanh(x) = 1 - 2/(exp2(2x*log2e)+1); saturates correctly at +-inf
    float e = __builtin_amdgcn_exp2f(x * 2.88539008177793f);
    return 1.0f - 2.0f * __builtin_amdgcn_rcpf(e + 1.0f);
}

// ---------------------------------------------------------------------------
// Prep 1: W = [W_h; W_c] -> bf16, tiled [kt][col][kk] (col-major per tile),
// XOR-swizzled (byte ^= (col&7)<<4) so GEMM stages it with LINEAR
// global_load_lds and reads conflict-free with the same swizzle.
// ---------------------------------------------------------------------------
__global__ void kprep_w(const float* __restrict__ Wh, const float* __restrict__ Wc,
                        unsigned short* __restrict__ wt) {
    int c   = blockIdx.x * blockDim.x + threadIdx.x;   // 65536 16B-chunks
    int col = c & 511;
    int kk8 = (c >> 9) & 7;
    int kt  = c >> 12;
    int kbase = kt * 64 + kk8 * 8;
    unsigned short tmp[8];
#pragma unroll
    for (int j = 0; j < 8; ++j) {
        int kg = kbase + j;
        float w = (kg < 512) ? Wh[kg * 512 + col] : Wc[(kg - 512) * 512 + col];
        tmp[j] = f2bf(w);
    }
    unsigned byteoff = (unsigned)(col * 128 + kk8 * 16) ^ ((unsigned)(col & 7) << 4);
    unsigned short* dst = wt + (size_t)kt * (512 * 64) + byteoff / 2;
    *reinterpret_cast<uint4*>(dst) = *reinterpret_cast<const uint4*>(tmp);
}

// ---------------------------------------------------------------------------
// Prep 2: q[b][h] = dec[b]@W_s + b_h + b_s + b_c   (fp32, tiny GEMV)
// ---------------------------------------------------------------------------
__global__ void kprep_q(const float* __restrict__ dec, const float* __restrict__ Ws,
                        const float* __restrict__ bh, const float* __restrict__ bs,
                        const float* __restrict__ bc, float* __restrict__ q) {
    __shared__ float dsh[512];
    int b = blockIdx.x, t = threadIdx.x;               // 256 threads
    dsh[t]       = dec[b * 512 + t];
    dsh[t + 256] = dec[b * 512 + 256 + t];
    __syncthreads();
    float a0 = 0.f, a1 = 0.f;
#pragma unroll 4
    for (int k = 0; k < 512; ++k) {
        float d = dsh[k];
        a0 = fmaf(d, Ws[k * 512 + t], a0);
        a1 = fmaf(d, Ws[k * 512 + 256 + t], a1);
    }
    q[b * 512 + t]       = a0 + bh[t] + bs[t] + bc[t];
    q[b * 512 + 256 + t] = a1 + bh[256 + t] + bs[256 + t] + bc[256 + t];
}

// ---------------------------------------------------------------------------
// Main fused GEMM: x = [enc|cov] @ [W_h;W_c] + q ; e = tanh(x) ; score = e@v
// BM=128 rows/WG, full N=512, K-loop over 16 tiles of BK=64.
// 8 waves (2Mx4N), per-wave 64x128, 16x16x32 bf16 MFMA.
// ---------------------------------------------------------------------------
__launch_bounds__(512, 2)
__global__ void kgemm(const float* __restrict__ enc, const float* __restrict__ cov,
                      const unsigned short* __restrict__ wt,
                      const float* __restrict__ q, const float* __restrict__ vvec,
                      float* __restrict__ scores) {
    __shared__ unsigned short Asm[BM * BK];     // 16 KB, [row][k] swizzled
    __shared__ unsigned short Bsm[H2 * BK];     // 64 KB, [col][k] swizzled
    __shared__ float qv[H2];
    __shared__ float vv[H2];
    __shared__ float sred[BM][4];

    int tid  = threadIdx.x;
    int wid  = tid >> 6, lane = tid & 63;
    int wm   = wid >> 2, wn = wid & 3;

    // XCD-aware bijective swizzle (nwg = 1024 divisible by 8)
    int bidx = blockIdx.x;
    int cpx  = gridDim.x >> 3;
    int swz  = (bidx & 7) * cpx + (bidx >> 3);

    int row0 = swz * BM;                         // flat (b,s) row
    const float* encb = enc + (size_t)row0 * H2;
    const float* covb = cov + (size_t)row0 * H2;

    if (tid < 512) { qv[tid] = q[(row0 >> 12) * 512 + tid]; vv[tid] = vvec[tid]; }

    f32x4 acc[4][8] = {};

    int arow = tid >> 2;                         // 0..127
    int kq   = (tid & 3) * 16;                   // 0,16,32,48
    unsigned awb0 = ((unsigned)(arow * 128 + kq * 2))      ^ ((unsigned)(arow & 7) << 4);
    unsigned awb1 = ((unsigned)(arow * 128 + kq * 2 + 16)) ^ ((unsigned)(arow & 7) << 4);

    for (int kt = 0; kt < NKT; ++kt) {
        // ---- stage A (fp32 -> bf16, swizzled ds_write_b128) ----
        {
            const float* src = (kt < 8) ? (encb + (size_t)arow * H2 + kt * 64 + kq)
                                        : (covb + (size_t)arow * H2 + (kt - 8) * 64 + kq);
            float fv[16];
            *reinterpret_cast<f32x4*>(fv)      = *reinterpret_cast<const f32x4*>(src);
            *reinterpret_cast<f32x4*>(fv + 4)  = *reinterpret_cast<const f32x4*>(src + 4);
            *reinterpret_cast<f32x4*>(fv + 8)  = *reinterpret_cast<const f32x4*>(src + 8);
            *reinterpret_cast<f32x4*>(fv + 12) = *reinterpret_cast<const f32x4*>(src + 12);
            unsigned short hv[16];
#pragma unroll
            for (int j = 0; j < 16; ++j) hv[j] = f2bf(fv[j]);
            *reinterpret_cast<uint4*>((char*)Asm + awb0) = *reinterpret_cast<const uint4*>(hv);
            *reinterpret_cast<uint4*>((char*)Asm + awb1) = *reinterpret_cast<const uint4*>(hv + 8);
        }
        // ---- stage B (pre-swizzled bf16 weights, linear global_load_lds x16B) ----
        {
            const unsigned short* gt = wt + (size_t)kt * (512 * 64) + wid * 4096 + lane * 8;
#pragma unroll
            for (int i = 0; i < 8; ++i) {
                __builtin_amdgcn_global_load_lds((as1_uint*)(gt + i * 512),
                                                 (as3_uint*)(Bsm + wid * 4096 + i * 512),
                                                 16, 0, 0);
            }
        }
        __syncthreads();
        // ---- compute: 2 k32-steps, 32 MFMA each per wave ----
#pragma unroll
        for (int ks = 0; ks < 2; ++ks) {
            bf16x8 af[4], bfr[8];
#pragma unroll
            for (int mi = 0; mi < 4; ++mi) {
                int row = wm * 64 + mi * 16 + (lane & 15);
                unsigned bo = ((unsigned)(row * 128 + ks * 64 + (lane >> 4) * 16))
                              ^ ((unsigned)(row & 7) << 4);
                af[mi] = *reinterpret_cast<const bf16x8*>((const char*)Asm + bo);
            }
#pragma unroll
            for (int ni = 0; ni < 8; ++ni) {
                int col = wn * 128 + ni * 16 + (lane & 15);
                unsigned bo = ((unsigned)(col * 128 + ks * 64 + (lane >> 4) * 16))
                              ^ ((unsigned)(col & 7) << 4);
                bfr[ni] = *reinterpret_cast<const bf16x8*>((const char*)Bsm + bo);
            }
#pragma unroll
            for (int mi = 0; mi < 4; ++mi)
#pragma unroll
                for (int ni = 0; ni < 8; ++ni)
                    acc[mi][ni] = __builtin_amdgcn_mfma_f32_16x16x32_bf16(
                        af[mi], bfr[ni], acc[mi][ni], 0, 0, 0);
        }
        __syncthreads();
    }

    // ---- epilogue: tanh(x + q) * v, reduce over 512 cols -> scores ----
    float ps[4][4] = {};
#pragma unroll
    for (int mi = 0; mi < 4; ++mi)
#pragma unroll
        for (int ni = 0; ni < 8; ++ni) {
            int colg = wn * 128 + ni * 16 + (lane & 15);
            float qq = qv[colg], vl = vv[colg];
#pragma unroll
            for (int j = 0; j < 4; ++j) {
                float e = fast_tanh(acc[mi][ni][j] + qq);
                ps[mi][j] = fmaf(e, vl, ps[mi][j]);
            }
        }
#pragma unroll
    for (int mi = 0; mi < 4; ++mi)
#pragma unroll
        for (int j = 0; j < 4; ++j) {
            float s = ps[mi][j];
            s += __shfl_xor(s, 1);
            s += __shfl_xor(s, 2);
            s += __shfl_xor(s, 4);
            s += __shfl_xor(s, 8);
            if ((lane & 15) == 0)
                sred[wm * 64 + mi * 16 + (lane >> 4) * 4 + j][wn] = s;
        }
    __syncthreads();
    if (tid < BM) {
        float s = sred[tid][0] + sred[tid][1] + sred[tid][2] + sred[tid][3];
        scores[row0 + tid] = s;
    }
}

// ---------------------------------------------------------------------------
// Softmax over S per batch; also zeroes h_star (atomic target for kcov).
// ---------------------------------------------------------------------------
__global__ void ksoftmax(const float* __restrict__ scores, float* __restrict__ out) {
    __shared__ float redm[16];
    __shared__ float reds[16];
    int b = blockIdx.x, t = threadIdx.x, lane = t & 63, w = t >> 6;  // 1024 thr
    if (t < 512) out[b * 512 + t] = 0.0f;                            // zero h_star
    f32x4 sv = *reinterpret_cast<const f32x4*>(scores + b * 4096 + t * 4);
    float m = fmaxf(fmaxf(sv[0], sv[1]), fmaxf(sv[2], sv[3]));
#pragma unroll
    for (int o = 1; o < 64; o <<= 1) m = fmaxf(m, __shfl_xor(m, o));
    if (lane == 0) redm[w] = m;
    __syncthreads();
    float mm = redm[0];
#pragma unroll
    for (int i = 1; i < 16; ++i) mm = fmaxf(mm, redm[i]);

    f32x4 p;
#pragma unroll
    for (int j = 0; j < 4; ++j)
        p[j] = __builtin_amdgcn_exp2f((sv[j] - mm) * 1.4426950408889634f);
    float s = p[0] + p[1] + p[2] + p[3];
#pragma unroll
    for (int o = 1; o < 64; o <<= 1) s += __shfl_xor(s, o);
    if (lane == 0) reds[w] = s;
    __syncthreads();
    float tot = 0.f;
#pragma unroll
    for (int i = 0; i < 16; ++i) tot += reds[i];
    float rinv = __builtin_amdgcn_rcpf(tot);
    p *= rinv;
    *reinterpret_cast<f32x4*>(out + 16384 + b * 4096 + t * 4) = p;
}

// ---------------------------------------------------------------------------
// coverage_new = cov + attn (broadcast) ; h_star = sum_s attn * enc (atomic)
// ---------------------------------------------------------------------------
__global__ void kcov(const float* __restrict__ enc, const float* __restrict__ cov,
                     float* __restrict__ out) {
    const float* attn = out + 16384;
    float* covn  = out + 16384 + 131072;
    float* hstar = out;
    int blk = blockIdx.x;                    // 2048 = 32 b * 64 chunks
    int b = blk >> 6, ck = blk & 63;
    int s0 = ck * 64;
    int t  = threadIdx.x;                    // 256
    int f4 = (t & 127) * 4;
    int rp = t >> 7;
    size_t base = (size_t)b * SEQ * H2;
    f32x4 h = {0.f, 0.f, 0.f, 0.f};
#pragma unroll 2
    for (int i = 0; i < 32; ++i) {
        int s = s0 + i * 2 + rp;
        float a = attn[b * 4096 + s];
        size_t idx = base + (size_t)s * H2 + f4;
        f32x4 e4 = *reinterpret_cast<const f32x4*>(enc + idx);
        f32x4 c4 = *reinterpret_cast<const f32x4*>(cov + idx);
        c4 += a;
        __builtin_nontemporal_store(c4, reinterpret_cast<f32x4*>(covn + idx));
        h += a * e4;
    }
    int off = b * 512 + f4;
    atomicAdd(&hstar[off + 0], h[0]);
    atomicAdd(&hstar[off + 1], h[1]);
    atomicAdd(&hstar[off + 2], h[2]);
    atomicAdd(&hstar[off + 3], h[3]);
}

extern "C" void kernel_launch(void* const* d_in, const int* in_sizes, int n_in,
                              void* d_out, int out_size, void* d_ws, size_t ws_size,
                              hipStream_t stream) {
    const float* dec = (const float*)d_in[0];
    const float* enc = (const float*)d_in[1];
    const float* cov = (const float*)d_in[2];
    const float* Wh  = (const float*)d_in[3];
    const float* bh  = (const float*)d_in[4];
    const float* Ws  = (const float*)d_in[5];
    const float* bs  = (const float*)d_in[6];
    const float* Wc  = (const float*)d_in[7];
    const float* bc  = (const float*)d_in[8];
    const float* v   = (const float*)d_in[9];
    float* out = (float*)d_out;

    char* ws = (char*)d_ws;
    unsigned short* wt = (unsigned short*)ws;                 // 1 MB bf16 weights
    float* q      = (float*)(ws + (1 << 20));                 // 64 KB
    float* scores = (float*)(ws + (1 << 20) + 65536);         // 512 KB

    kprep_w <<<dim3(256),  dim3(256),  0, stream>>>(Wh, Wc, wt);
    kprep_q <<<dim3(32),   dim3(256),  0, stream>>>(dec, Ws, bh, bs, bc, q);
    kgemm   <<<dim3(1024), dim3(512),  0, stream>>>(enc, cov, wt, q, v, scores);
    ksoftmax<<<dim3(32),   dim3(1024), 0, stream>>>(scores, out);
    kcov    <<<dim3(2048), dim3(256),  0, stream>>>(enc, cov, out);
}

// Round 2
// 401.503 us; speedup vs baseline: 1.0858x; 1.0858x over previous
//
#include <hip/hip_runtime.h>
#include <hip/hip_bf16.h>
#include <stdint.h>

#define H2    512
#define BATCH 32
#define SEQ   4096
#define BM    64
#define BK    64
#define NKT   16          // K-tiles: 1024 / 64

typedef __attribute__((ext_vector_type(4))) float f32x4;
typedef __attribute__((ext_vector_type(8))) short bf16x8;

// RNE fp32 -> bf16
__device__ __forceinline__ unsigned short f2bf(float f) {
    union { float f; unsigned u; } v; v.f = f;
    unsigned r = v.u + 0x7FFF + ((v.u >> 16) & 1);
    return (unsigned short)(r >> 16);
}

__device__ __forceinline__ float fast_tanh(float x) {
    float e = __builtin_amdgcn_exp2f(x * 2.88539008177793f);
    return 1.0f - 2.0f * __builtin_amdgcn_rcpf(e + 1.0f);
}

// ---------------------------------------------------------------------------
// Prep 1: W = [W_h; W_c] -> bf16 in FRAGMENT-MAJOR order:
// chunk c = ((kt*2+ks)*32 + cb)*64 + lane  holds 16B:
//   B[col = cb*16 + (lane&15)][k = kt*64 + ks*32 + (lane>>4)*8 + j], j=0..7
// so a wave's MFMA B-fragment load is 64 lanes x 16B = 1KB contiguous.
// ---------------------------------------------------------------------------
__global__ void kprep_w(const float* __restrict__ Wh, const float* __restrict__ Wc,
                        unsigned short* __restrict__ wt) {
    int c    = blockIdx.x * blockDim.x + threadIdx.x;   // 65536 chunks
    int lane = c & 63;
    int cb   = (c >> 6) & 31;
    int ks   = (c >> 11) & 1;
    int kt   = c >> 12;
    int col  = cb * 16 + (lane & 15);
    int k0   = kt * 64 + ks * 32 + (lane >> 4) * 8;
    unsigned short tmp[8];
#pragma unroll
    for (int j = 0; j < 8; ++j) {
        int kg = k0 + j;
        float w = (kg < 512) ? Wh[kg * 512 + col] : Wc[(kg - 512) * 512 + col];
        tmp[j] = f2bf(w);
    }
    *reinterpret_cast<uint4*>(wt + (size_t)c * 8) = *reinterpret_cast<const uint4*>(tmp);
}

// ---------------------------------------------------------------------------
// Prep 2: q[b][h] = dec[b]@W_s + b_h + b_s + b_c   (fp32, tiny GEMV)
// ---------------------------------------------------------------------------
__global__ void kprep_q(const float* __restrict__ dec, const float* __restrict__ Ws,
                        const float* __restrict__ bh, const float* __restrict__ bs,
                        const float* __restrict__ bc, float* __restrict__ q) {
    __shared__ float dsh[512];
    int b = blockIdx.x, t = threadIdx.x;               // 256 threads
    dsh[t]       = dec[b * 512 + t];
    dsh[t + 256] = dec[b * 512 + 256 + t];
    __syncthreads();
    float a0 = 0.f, a1 = 0.f;
#pragma unroll 4
    for (int k = 0; k < 512; ++k) {
        float d = dsh[k];
        a0 = fmaf(d, Ws[k * 512 + t], a0);
        a1 = fmaf(d, Ws[k * 512 + 256 + t], a1);
    }
    q[b * 512 + t]       = a0 + bh[t] + bs[t] + bc[t];
    q[b * 512 + 256 + t] = a1 + bh[256 + t] + bs[256 + t] + bc[256 + t];
}

// ---------------------------------------------------------------------------
// Main fused GEMM: x = [enc|cov] @ [W_h;W_c] + q ; e = tanh(x) ; score = e@v
// BM=64 rows/WG, full N=512 (A read exactly once), K-loop 16 tiles of 64.
// 8 waves, 1Mx8N: per-wave 64x64 output -> 64-reg accumulator.
// A: reg-staged fp32->bf16 into double-buffered swizzled LDS (8KB/buf).
// B: fragment-major from global (L2-resident, 1KB/фrag coalesced), no LDS.
// ---------------------------------------------------------------------------
__launch_bounds__(512, 4)
__global__ void kgemm(const float* __restrict__ enc, const float* __restrict__ cov,
                      const unsigned short* __restrict__ wt,
                      const float* __restrict__ q, const float* __restrict__ vvec,
                      float* __restrict__ scores) {
    __shared__ unsigned short Asm[2][BM * BK];   // 2 x 8KB, [row][k] swizzled
    __shared__ float qv[H2];
    __shared__ float vv[H2];
    __shared__ float sred[BM][8];

    int tid  = threadIdx.x;
    int lane = tid & 63, wn = tid >> 6;

    // XCD-aware bijective swizzle (2048 % 8 == 0)
    int cpx  = gridDim.x >> 3;
    int swz  = (blockIdx.x & 7) * cpx + (blockIdx.x >> 3);
    int row0 = swz * BM;                         // flat (b,s) row

    qv[tid] = q[(row0 >> 12) * H2 + tid];
    vv[tid] = vvec[tid];

    // A staging addressing: thread t stages row r = t>>3, k-octet k8 = t&7
    int r = tid >> 3, k8 = tid & 7;
    const float* ae = enc + (size_t)(row0 + r) * H2 + k8 * 8;
    const float* ac = cov + (size_t)(row0 + r) * H2 + k8 * 8;
    unsigned awb = (unsigned)(r * 128 + ((k8 * 16) ^ ((r & 7) << 4)));

    // per-lane A-frag read offsets (row = mi*16 + (lane&15); +mi*2048 at use)
    unsigned arb0 = (unsigned)((lane & 15) * 128 +
                    ((((lane >> 4) << 4))      ^ ((lane & 7) << 4)));
    unsigned arb1 = (unsigned)((lane & 15) * 128 +
                    (((64 + ((lane >> 4) << 4))) ^ ((lane & 7) << 4)));

    f32x4 acc[4][4] = {};

    // prologue: stage tile 0
    {
        f32x4 a0 = *reinterpret_cast<const f32x4*>(ae);
        f32x4 a1 = *reinterpret_cast<const f32x4*>(ae + 4);
        union { unsigned short h[8]; uint4 u; } t;
#pragma unroll
        for (int j = 0; j < 4; ++j) { t.h[j] = f2bf(a0[j]); t.h[4 + j] = f2bf(a1[j]); }
        *reinterpret_cast<uint4*>((char*)Asm[0] + awb) = t.u;
    }
    __syncthreads();

    for (int kt = 0; kt < NKT; ++kt) {
        int cur = kt & 1;
        // ---- issue B fragment loads (8 x 16B/lane, contiguous 1KB/wave) ----
        bf16x8 bfr[2][4];
        const bf16x8* bp0 = reinterpret_cast<const bf16x8*>(wt) +
                            ((size_t)(kt * 2 + 0) * 32 + wn * 4) * 64 + lane;
        const bf16x8* bp1 = reinterpret_cast<const bf16x8*>(wt) +
                            ((size_t)(kt * 2 + 1) * 32 + wn * 4) * 64 + lane;
#pragma unroll
        for (int ni = 0; ni < 4; ++ni) bfr[0][ni] = bp0[ni * 64];
#pragma unroll
        for (int ni = 0; ni < 4; ++ni) bfr[1][ni] = bp1[ni * 64];
        // ---- issue A prefetch for kt+1 (stays in flight across MFMAs) ----
        f32x4 p0, p1;
        if (kt + 1 < NKT) {
            const float* src = (kt + 1 < 8) ? (ae + (kt + 1) * 64) : (ac + (kt - 7) * 64);
            p0 = *reinterpret_cast<const f32x4*>(src);
            p1 = *reinterpret_cast<const f32x4*>(src + 4);
        }
        // ---- compute: 2 k32-steps, 16 MFMA each per wave ----
#pragma unroll
        for (int ks = 0; ks < 2; ++ks) {
            bf16x8 af[4];
#pragma unroll
            for (int mi = 0; mi < 4; ++mi)
                af[mi] = *reinterpret_cast<const bf16x8*>(
                    (const char*)Asm[cur] + mi * 2048 + (ks ? arb1 : arb0));
#pragma unroll
            for (int mi = 0; mi < 4; ++mi)
#pragma unroll
                for (int ni = 0; ni < 4; ++ni)
                    acc[mi][ni] = __builtin_amdgcn_mfma_f32_16x16x32_bf16(
                        af[mi], bfr[ks][ni], acc[mi][ni], 0, 0, 0);
        }
        // ---- convert + stage A(kt+1) into other buffer ----
        if (kt + 1 < NKT) {
            union { unsigned short h[8]; uint4 u; } t;
#pragma unroll
            for (int j = 0; j < 4; ++j) { t.h[j] = f2bf(p0[j]); t.h[4 + j] = f2bf(p1[j]); }
            *reinterpret_cast<uint4*>((char*)Asm[cur ^ 1] + awb) = t.u;
        }
        __syncthreads();
    }

    // ---- epilogue: tanh(x + q) * v, reduce over 512 cols -> scores ----
    float ps[4][4] = {};
#pragma unroll
    for (int mi = 0; mi < 4; ++mi)
#pragma unroll
        for (int ni = 0; ni < 4; ++ni) {
            int colg = wn * 64 + ni * 16 + (lane & 15);
            float qq = qv[colg], vl = vv[colg];
#pragma unroll
            for (int j = 0; j < 4; ++j) {
                float e = fast_tanh(acc[mi][ni][j] + qq);
                ps[mi][j] = fmaf(e, vl, ps[mi][j]);
            }
        }
#pragma unroll
    for (int mi = 0; mi < 4; ++mi)
#pragma unroll
        for (int j = 0; j < 4; ++j) {
            float s = ps[mi][j];
            s += __shfl_xor(s, 1);
            s += __shfl_xor(s, 2);
            s += __shfl_xor(s, 4);
            s += __shfl_xor(s, 8);
            if ((lane & 15) == 0)
                sred[mi * 16 + (lane >> 4) * 4 + j][wn] = s;
        }
    __syncthreads();
    if (tid < BM) {
        float s = 0.f;
#pragma unroll
        for (int w = 0; w < 8; ++w) s += sred[tid][w];
        scores[row0 + tid] = s;
    }
}

// ---------------------------------------------------------------------------
// Softmax over S per batch; also zeroes h_star (atomic target for kcov).
// ---------------------------------------------------------------------------
__global__ void ksoftmax(const float* __restrict__ scores, float* __restrict__ out) {
    __shared__ float redm[16];
    __shared__ float reds[16];
    int b = blockIdx.x, t = threadIdx.x, lane = t & 63, w = t >> 6;  // 1024 thr
    if (t < 512) out[b * 512 + t] = 0.0f;                            // zero h_star
    f32x4 sv = *reinterpret_cast<const f32x4*>(scores + b * 4096 + t * 4);
    float m = fmaxf(fmaxf(sv[0], sv[1]), fmaxf(sv[2], sv[3]));
#pragma unroll
    for (int o = 1; o < 64; o <<= 1) m = fmaxf(m, __shfl_xor(m, o));
    if (lane == 0) redm[w] = m;
    __syncthreads();
    float mm = redm[0];
#pragma unroll
    for (int i = 1; i < 16; ++i) mm = fmaxf(mm, redm[i]);

    f32x4 p;
#pragma unroll
    for (int j = 0; j < 4; ++j)
        p[j] = __builtin_amdgcn_exp2f((sv[j] - mm) * 1.4426950408889634f);
    float s = p[0] + p[1] + p[2] + p[3];
#pragma unroll
    for (int o = 1; o < 64; o <<= 1) s += __shfl_xor(s, o);
    if (lane == 0) reds[w] = s;
    __syncthreads();
    float tot = 0.f;
#pragma unroll
    for (int i = 0; i < 16; ++i) tot += reds[i];
    float rinv = __builtin_amdgcn_rcpf(tot);
    p *= rinv;
    *reinterpret_cast<f32x4*>(out + 16384 + b * 4096 + t * 4) = p;
}

// ---------------------------------------------------------------------------
// coverage_new = cov + attn (broadcast) ; h_star = sum_s attn * enc (atomic)
// ---------------------------------------------------------------------------
__global__ void kcov(const float* __restrict__ enc, const float* __restrict__ cov,
                     float* __restrict__ out) {
    const float* attn = out + 16384;
    float* covn  = out + 16384 + 131072;
    float* hstar = out;
    int blk = blockIdx.x;                    // 2048 = 32 b * 64 chunks
    int b = blk >> 6, ck = blk & 63;
    int s0 = ck * 64;
    int t  = threadIdx.x;                    // 256
    int f4 = (t & 127) * 4;
    int rp = t >> 7;
    size_t base = (size_t)b * SEQ * H2;
    f32x4 h = {0.f, 0.f, 0.f, 0.f};
#pragma unroll 2
    for (int i = 0; i < 32; ++i) {
        int s = s0 + i * 2 + rp;
        float a = attn[b * 4096 + s];
        size_t idx = base + (size_t)s * H2 + f4;
        f32x4 e4 = *reinterpret_cast<const f32x4*>(enc + idx);
        f32x4 c4 = *reinterpret_cast<const f32x4*>(cov + idx);
        c4 += a;
        __builtin_nontemporal_store(c4, reinterpret_cast<f32x4*>(covn + idx));
        h += a * e4;
    }
    int off = b * 512 + f4;
    atomicAdd(&hstar[off + 0], h[0]);
    atomicAdd(&hstar[off + 1], h[1]);
    atomicAdd(&hstar[off + 2], h[2]);
    atomicAdd(&hstar[off + 3], h[3]);
}

extern "C" void kernel_launch(void* const* d_in, const int* in_sizes, int n_in,
                              void* d_out, int out_size, void* d_ws, size_t ws_size,
                              hipStream_t stream) {
    const float* dec = (const float*)d_in[0];
    const float* enc = (const float*)d_in[1];
    const float* cov = (const float*)d_in[2];
    const float* Wh  = (const float*)d_in[3];
    const float* bh  = (const float*)d_in[4];
    const float* Ws  = (const float*)d_in[5];
    const float* bs  = (const float*)d_in[6];
    const float* Wc  = (const float*)d_in[7];
    const float* bc  = (const float*)d_in[8];
    const float* v   = (const float*)d_in[9];
    float* out = (float*)d_out;

    char* ws = (char*)d_ws;
    unsigned short* wt = (unsigned short*)ws;                 // 1 MB bf16 weights
    float* q      = (float*)(ws + (1 << 20));                 // 64 KB
    float* scores = (float*)(ws + (1 << 20) + 65536);         // 512 KB

    kprep_w <<<dim3(256),  dim3(256),  0, stream>>>(Wh, Wc, wt);
    kprep_q <<<dim3(32),   dim3(256),  0, stream>>>(dec, Ws, bh, bs, bc, q);
    kgemm   <<<dim3(2048), dim3(512),  0, stream>>>(enc, cov, wt, q, v, scores);
    ksoftmax<<<dim3(32),   dim3(1024), 0, stream>>>(scores, out);
    kcov    <<<dim3(2048), dim3(256),  0, stream>>>(enc, cov, out);
}